// Round 2
// baseline (724.397 us; speedup 1.0000x reference)
//
#include <hip/hip_runtime.h>
#include <cstdint>

typedef __bf16 v8bf __attribute__((ext_vector_type(8)));
typedef float  v4f  __attribute__((ext_vector_type(4)));

// ---------- fully fused: out[h][n][m] = leaky(sum_d z0[n][d]*W[h][d]*z1[m][d] + bias[h]) ----
// NO workspace: using d_ws triggers a 2 GiB poison fill (~350 us @ 6.2 TB/s) inside the
// timed window every iteration. Conversion f32->bf16 is fused into the GEMM instead.
//
// 1-D grid of 8192 blocks, 256 threads (4 waves); tile 128x128, BK=64, 4 K-steps,
// double-buffered LDS (2 x (16+16) KiB = 64 KiB -> 2 blocks/CU), 1 barrier per K-step.
//
// XCD swizzle (T1): id%8 = XCD; work = (id%8)*1024 + id/8 -> each XCD owns 16 consecutive
// h values (bijective: 8192 % 8 == 0).
//
// LDS swizzle (T2, rule 21 both-sides): rows are 64 bf16 = 128 B = 8 x 16B slots; slot is
// XORed with (row&7) on the ds_write AND the ds_read (same involution). Both write and
// read land 8 lanes per 4-bank group with distinct rows = 2 lanes/bank = conflict-free.
//
// Staging (T14 issue-early / write-late): threads 0..127 own A row t (z0*W), threads
// 128..255 own B row t-128 (z1). Next K-step's 16x global_load_dwordx4 are issued BEFORE
// the MFMA phase; the convert+ds_write happens after. z0/z1/W total 2.1 MiB -> per-XCD
// L2-resident, ~200 cy hit latency hidden under ~600+ cy of MFMA.
__global__ __launch_bounds__(256)
void fused_gemm(const float* __restrict__ z0, const float* __restrict__ z1,
                const float* __restrict__ W, const float* __restrict__ bias,
                float* __restrict__ out)
{
    __shared__ __align__(16) uint16_t aT[2][128 * 64];   // z0*W rows [n][k], 128B rows
    __shared__ __align__(16) uint16_t bT[2][128 * 64];   // z1   rows [m][k], 128B rows

    const int t = threadIdx.x, wave = t >> 6, lane = t & 63;

    const int wg   = blockIdx.x;
    const int work = ((wg & 7) << 10) | (wg >> 3);
    const int h    = work >> 6;
    const int n0   = ((work >> 3) & 7) << 7;
    const int m0   = (work & 7) << 7;

    const float* Wr = W + h * 256;

    // ---- staging role: 128 A-threads (rows of z0*W), 128 B-threads (rows of z1) ----
    const bool isA = (t < 128);
    const int  srow = t & 127;
    const int  sx7  = srow & 7;
    const float* src = (isA ? z0 + ((size_t)n0 << 8) : z1 + ((size_t)m0 << 8))
                       + ((size_t)srow << 8);

    float4 g[16];   // in-flight K-step (64 f32 = one row-slice)

    // convert current g (scaled by W if A-role) and write swizzled 16B slots
    auto convert_write = [&](uint16_t* dst, int k0) {
#pragma unroll
        for (int s = 0; s < 8; ++s) {
            float4 u = g[2 * s], v = g[2 * s + 1];
            if (isA) {
                float4 wu = *(const float4*)(Wr + k0 + s * 8);
                float4 wv = *(const float4*)(Wr + k0 + s * 8 + 4);
                u.x *= wu.x; u.y *= wu.y; u.z *= wu.z; u.w *= wu.w;
                v.x *= wv.x; v.y *= wv.y; v.z *= wv.z; v.w *= wv.w;
            }
            v8bf pk;
            pk[0] = (__bf16)u.x; pk[1] = (__bf16)u.y; pk[2] = (__bf16)u.z; pk[3] = (__bf16)u.w;
            pk[4] = (__bf16)v.x; pk[5] = (__bf16)v.y; pk[6] = (__bf16)v.z; pk[7] = (__bf16)v.w;
            *(v8bf*)&dst[(srow << 6) + ((s ^ sx7) << 3)] = pk;
        }
    };

    v4f acc[4][4];
#pragma unroll
    for (int r = 0; r < 4; ++r)
#pragma unroll
        for (int c = 0; c < 4; ++c) acc[r][c] = (v4f){0.f, 0.f, 0.f, 0.f};

    const int mbw = (wave & 1) * 64;   // wave's m sub-block (MFMA A-operand side)
    const int nb  = (wave >> 1) * 64;  // wave's n sub-block (MFMA B-operand side)
    const int fr  = lane & 15;
    const int q   = lane >> 4;
    const int sx  = fr & 7;            // row&7 for read-side swizzle

    // ---- prologue: stage K-step 0 into buf 0 ----
#pragma unroll
    for (int i = 0; i < 16; ++i) g[i] = *(const float4*)(src + i * 4);
    convert_write(isA ? aT[0] : bT[0], 0);
    __syncthreads();

#pragma unroll
    for (int ks = 0; ks < 4; ++ks) {
        const int cur = ks & 1, nxt = cur ^ 1;

        // T14: issue next K-step's loads before compute (latency hides under MFMA)
        if (ks < 3) {
            const int k0n = (ks + 1) * 64;
#pragma unroll
            for (int i = 0; i < 16; ++i) g[i] = *(const float4*)(src + k0n + i * 4);
        }

        // ---- compute from buf[cur] ----
#pragma unroll
        for (int ksl = 0; ksl < 2; ++ksl) {
            const int ko = ((((ksl << 2) | q) ^ sx) << 3);   // swizzled read slot
            v8bf am[4], bn[4];
#pragma unroll
            for (int r = 0; r < 4; ++r)
                am[r] = *(const v8bf*)&bT[cur][(mbw + r * 16 + fr) * 64 + ko];
#pragma unroll
            for (int c = 0; c < 4; ++c)
                bn[c] = *(const v8bf*)&aT[cur][(nb + c * 16 + fr) * 64 + ko];
#pragma unroll
            for (int r = 0; r < 4; ++r)
#pragma unroll
                for (int c = 0; c < 4; ++c)
                    acc[r][c] = __builtin_amdgcn_mfma_f32_16x16x32_bf16(am[r], bn[c], acc[r][c], 0, 0, 0);
        }

        // write-late: convert in-flight regs and store into the other buffer
        if (ks < 3)
            convert_write(isA ? aT[nxt] : bT[nxt], (ks + 1) * 64);

        __syncthreads();   // one barrier per K-step covers both buffer hand-offs
    }

    // ---- epilogue: D[row=m][col=n]; row=(lane>>4)*4+reg, col=lane&15 (m89/m97-verified) --
    const float bsf = bias[h];
    float* outB = out + ((size_t)h << 20) + ((size_t)n0 << 10) + m0;
    const int mq = (lane >> 4) * 4;
#pragma unroll
    for (int r = 0; r < 4; ++r) {
#pragma unroll
        for (int c = 0; c < 4; ++c) {
            const int n = nb + c * 16 + fr;
            const int m = mbw + r * 16 + mq;
            float4 o;
            float v0 = acc[r][c][0] + bsf; o.x = (v0 >= 0.f) ? v0 : 0.2f * v0;
            float v1 = acc[r][c][1] + bsf; o.y = (v1 >= 0.f) ? v1 : 0.2f * v1;
            float v2 = acc[r][c][2] + bsf; o.z = (v2 >= 0.f) ? v2 : 0.2f * v2;
            float v3 = acc[r][c][3] + bsf; o.w = (v3 >= 0.f) ? v3 : 0.2f * v3;
            *(float4*)(outB + ((size_t)n << 10) + m) = o;
        }
    }
}

extern "C" void kernel_launch(void* const* d_in, const int* in_sizes, int n_in,
                              void* d_out, int out_size, void* d_ws, size_t ws_size,
                              hipStream_t stream) {
    (void)in_sizes; (void)n_in; (void)out_size; (void)d_ws; (void)ws_size;
    const float* z0   = (const float*)d_in[0];
    const float* z1   = (const float*)d_in[1];
    const float* Wm   = (const float*)d_in[2];
    const float* bias = (const float*)d_in[3];
    float* out = (float*)d_out;

    fused_gemm<<<8192, 256, 0, stream>>>(z0, z1, Wm, bias, out);
}

// Round 5
// 649.792 us; speedup vs baseline: 1.1148x; 1.1148x over previous
//
#include <hip/hip_runtime.h>
#include <cstdint>

#define AS1 __attribute__((address_space(1)))
#define AS3 __attribute__((address_space(3)))

typedef __bf16 v8bf __attribute__((ext_vector_type(8)));
typedef float  v4f  __attribute__((ext_vector_type(4)));

__device__ __forceinline__ uint32_t f2u(float f) {
    union { float f; uint32_t u; } v; v.f = f; return v.u;
}
__device__ __forceinline__ uint16_t f2bf_rne(float f) {   // finite inputs
    uint32_t u = f2u(f);
    return (uint16_t)((u + 0x7FFFu + ((u >> 16) & 1u)) >> 16);
}
__device__ __forceinline__ uint32_t pack2(float a, float b) {
    return (uint32_t)f2bf_rne(a) | ((uint32_t)f2bf_rne(b) << 16);
}
// async global->LDS, 16B/lane; LDS dst = wave-uniform base (+lane*16 by HW)
__device__ __forceinline__ void async16(const void* g, void* l) {
    __builtin_amdgcn_global_load_lds((AS1 const void*)g, (AS3 void*)l, 16, 0, 0);
}

// ---------- prep: A_all[h][n][d] = bf16(z0[n][d]*W[h][d]); B_bf = bf16(z1) ----------
// blocks [0,16384): A_all (33.5M elems, 8/thread). blocks [16384,16512): z1 (262144 elems).
__global__ __launch_bounds__(256)
void prep_kernel(const float* __restrict__ z0, const float* __restrict__ z1,
                 const float* __restrict__ W,
                 uint16_t* __restrict__ Aall, uint16_t* __restrict__ Bbf)
{
    const int b = blockIdx.x;
    if (b < 16384) {
        const size_t e0 = ((size_t)b * 256 + threadIdx.x) * 8;
        const int h  = (int)(e0 >> 18);           // N*D = 2^18
        const int nd = (int)(e0 & 0x3FFFFu);
        const int d0 = (int)(e0 & 255u);
        float4 za = *(const float4*)(z0 + nd);
        float4 zb = *(const float4*)(z0 + nd + 4);
        float4 wa = *(const float4*)(W + h * 256 + d0);
        float4 wb = *(const float4*)(W + h * 256 + d0 + 4);
        uint4 r;
        r.x = pack2(za.x * wa.x, za.y * wa.y);
        r.y = pack2(za.z * wa.z, za.w * wa.w);
        r.z = pack2(zb.x * wb.x, zb.y * wb.y);
        r.w = pack2(zb.z * wb.z, zb.w * wb.w);
        *(uint4*)(Aall + e0) = r;
    } else {
        const size_t e0 = ((size_t)(b - 16384) * 256 + threadIdx.x) * 8;
        float4 za = *(const float4*)(z1 + e0);
        float4 zb = *(const float4*)(z1 + e0 + 4);
        uint4 r;
        r.x = pack2(za.x, za.y);
        r.y = pack2(za.z, za.w);
        r.z = pack2(zb.x, zb.y);
        r.w = pack2(zb.z, zb.w);
        *(uint4*)(Bbf + e0) = r;
    }
}

// ---------- GEMM: out[h][n][m] = leaky(sum_d Aall[h][n][d]*Bbf[m][d] + bias[h]) ----------
// 8192 blocks x 256 threads (4 waves); tile 128x128, BK=32, 8 K-steps,
// DOUBLE-buffered LDS at only 32 KiB total (2 x (8+8) KiB) -> 4 blocks/CU kept,
// ONE barrier per K-step (stage-next issued BEFORE compute, drain covered by MFMA+TLP).
//
// XCD swizzle (T1): work = (wg%8)*1024 + wg/8 -> each XCD owns 16 consecutive h
// (bijective, 8192%8==0); within a chunk m0 varies fastest -> A-panel L2 reuse.
//
// LDS swizzle (T2, rule 21): rows are 32 bf16 = 64 B = 4 x 16B slots. global_load_lds
// writes LINEAR LDS; the swizzle slot^=(row&3) is applied to the global SOURCE address
// and identically on the ds_read slot (same involution). Read banks: lanes (fr,q) land
// 8 lanes per 4-bank group, uniform = conflict-free (was 8-way, ~2.9x).
__global__ __launch_bounds__(256)
void gemm_kernel(const uint16_t* __restrict__ Aall, const uint16_t* __restrict__ Bbf,
                 const float* __restrict__ bias, float* __restrict__ out)
{
    __shared__ __align__(16) uint16_t aT[2][128 * 32];   // z0W rows [n][k], 64B rows
    __shared__ __align__(16) uint16_t bT[2][128 * 32];   // z1  rows [m][k], 64B rows

    const int t = threadIdx.x, wave = t >> 6, lane = t & 63;

    const int wg   = blockIdx.x;
    const int work = ((wg & 7) << 10) | (wg >> 3);
    const int h    = work >> 6;
    const int n0   = ((work >> 3) & 7) << 7;
    const int m0   = (work & 7) << 7;

    const uint16_t* Ab = Aall + ((size_t)h << 18) + ((size_t)n0 << 8);
    const uint16_t* Bb = Bbf + ((size_t)m0 << 8);

    // staging coords: thread covers (row = 64j + t>>2, slot = t&3); source pre-swizzled
    const int srow  = t >> 2;                       // 0..63 (call j adds 64)
    const int sslot = (t & 3) ^ (srow & 3);         // involution slot^=(row&3)
    const int sgoff = sslot << 3;                   // element offset of 16B slot
    const int ldsb  = (wave << 9);                  // wave*16 rows * 32 elems

    v4f acc[4][4];
#pragma unroll
    for (int r = 0; r < 4; ++r)
#pragma unroll
        for (int c = 0; c < 4; ++c) acc[r][c] = (v4f){0.f, 0.f, 0.f, 0.f};

    const int mbw = (wave & 1) * 64;   // wave's m sub-block (MFMA A-operand side)
    const int nb  = (wave >> 1) * 64;  // wave's n sub-block (MFMA B-operand side)
    const int fr  = lane & 15;
    const int ko  = (((lane >> 4) ^ (fr & 3)) << 3);   // swizzled read slot (row&3 = fr&3)

    // ---- prologue: stage K-step 0 into buf 0 ----
    async16(Ab + (size_t)srow * 256 + sgoff,        &aT[0][ldsb]);
    async16(Ab + (size_t)(srow + 64) * 256 + sgoff, &aT[0][2048 + ldsb]);
    async16(Bb + (size_t)srow * 256 + sgoff,        &bT[0][ldsb]);
    async16(Bb + (size_t)(srow + 64) * 256 + sgoff, &bT[0][2048 + ldsb]);
    __syncthreads();

#pragma unroll
    for (int ks = 0; ks < 8; ++ks) {
        const int cur = ks & 1, nxt = cur ^ 1;
        // T3-minimal: issue next K-step's loads BEFORE compute; single drain per step
        if (ks < 7) {
            const int kel = (ks + 1) * 32 + sgoff;
            async16(Ab + (size_t)srow * 256 + kel,        &aT[nxt][ldsb]);
            async16(Ab + (size_t)(srow + 64) * 256 + kel, &aT[nxt][2048 + ldsb]);
            async16(Bb + (size_t)srow * 256 + kel,        &bT[nxt][ldsb]);
            async16(Bb + (size_t)(srow + 64) * 256 + kel, &bT[nxt][2048 + ldsb]);
        }

        v8bf am[4], bn[4];
#pragma unroll
        for (int r = 0; r < 4; ++r)
            am[r] = *(const v8bf*)&bT[cur][(mbw + r * 16 + fr) * 32 + ko];
#pragma unroll
        for (int c = 0; c < 4; ++c)
            bn[c] = *(const v8bf*)&aT[cur][(nb + c * 16 + fr) * 32 + ko];
#pragma unroll
        for (int r = 0; r < 4; ++r)
#pragma unroll
            for (int c = 0; c < 4; ++c)
                acc[r][c] = __builtin_amdgcn_mfma_f32_16x16x32_bf16(am[r], bn[c], acc[r][c], 0, 0, 0);

        __syncthreads();   // one barrier/K-step: drains prefetch, covered by 16 MFMA + 4 blocks/CU TLP
    }

    // epilogue: D[row=m][col=n]; row = (lane>>4)*4 + reg, col = lane&15 (m89/m97-verified)
    const float bsf = bias[h];
    float* outB = out + ((size_t)h << 20) + ((size_t)n0 << 10) + m0;
    const int mq = (lane >> 4) * 4;
#pragma unroll
    for (int r = 0; r < 4; ++r) {
#pragma unroll
        for (int c = 0; c < 4; ++c) {
            const int n = nb + c * 16 + fr;
            const int m = mbw + r * 16 + mq;
            float4 o;
            float v0 = acc[r][c][0] + bsf; o.x = (v0 >= 0.f) ? v0 : 0.2f * v0;
            float v1 = acc[r][c][1] + bsf; o.y = (v1 >= 0.f) ? v1 : 0.2f * v1;
            float v2 = acc[r][c][2] + bsf; o.z = (v2 >= 0.f) ? v2 : 0.2f * v2;
            float v3 = acc[r][c][3] + bsf; o.w = (v3 >= 0.f) ? v3 : 0.2f * v3;
            *(float4*)(outB + ((size_t)n << 10) + m) = o;
        }
    }
}

// ---------- fallback: converts f32->bf16 in-kernel (no workspace) ----------
__global__ __launch_bounds__(256)
void gemm_fb(const float* __restrict__ z0, const float* __restrict__ z1,
             const float* __restrict__ W, const float* __restrict__ bias,
             float* __restrict__ out)
{
    __shared__ __align__(16) uint16_t aT[128 * 32];
    __shared__ __align__(16) uint16_t bT[128 * 32];
    const int t = threadIdx.x, wave = t >> 6, lane = t & 63;
    const int h = blockIdx.z, n0 = blockIdx.y * 128, m0 = blockIdx.x * 128;
    const float* Ab = z0 + (size_t)n0 * 256;
    const float* Bb = z1 + (size_t)m0 * 256;
    const int rowA = t >> 2, col8 = (t & 3) * 8;

    v4f acc[4][4];
#pragma unroll
    for (int r = 0; r < 4; ++r)
#pragma unroll
        for (int c = 0; c < 4; ++c) acc[r][c] = (v4f){0.f, 0.f, 0.f, 0.f};

    const int mbw = (wave & 1) * 64, nb = (wave >> 1) * 64;
    const int fr = lane & 15, kq = (lane >> 4) * 8;

    for (int ks = 0; ks < 8; ++ks) {
        const int k0 = ks * 32;
        float4 wa = *(const float4*)(W + h * 256 + k0 + col8);
        float4 wb = *(const float4*)(W + h * 256 + k0 + col8 + 4);
#pragma unroll
        for (int i = 0; i < 2; ++i) {
            const int row = i * 64 + rowA;
            float4 za = *(const float4*)(Ab + (size_t)row * 256 + k0 + col8);
            float4 zb = *(const float4*)(Ab + (size_t)row * 256 + k0 + col8 + 4);
            uint4 r;
            r.x = pack2(za.x * wa.x, za.y * wa.y);
            r.y = pack2(za.z * wa.z, za.w * wa.w);
            r.z = pack2(zb.x * wb.x, zb.y * wb.y);
            r.w = pack2(zb.z * wb.z, zb.w * wb.w);
            *(uint4*)&aT[(i * 256 + t) * 8] = r;
            float4 ba = *(const float4*)(Bb + (size_t)row * 256 + k0 + col8);
            float4 bb = *(const float4*)(Bb + (size_t)row * 256 + k0 + col8 + 4);
            uint4 s;
            s.x = pack2(ba.x, ba.y);
            s.y = pack2(ba.z, ba.w);
            s.z = pack2(bb.x, bb.y);
            s.w = pack2(bb.z, bb.w);
            *(uint4*)&bT[(i * 256 + t) * 8] = s;
        }
        __syncthreads();

        v8bf am[4], bn[4];
#pragma unroll
        for (int r = 0; r < 4; ++r)
            am[r] = *(const v8bf*)&bT[(mbw + r * 16 + fr) * 32 + kq];
#pragma unroll
        for (int c = 0; c < 4; ++c)
            bn[c] = *(const v8bf*)&aT[(nb + c * 16 + fr) * 32 + kq];
#pragma unroll
        for (int r = 0; r < 4; ++r)
#pragma unroll
            for (int c = 0; c < 4; ++c)
                acc[r][c] = __builtin_amdgcn_mfma_f32_16x16x32_bf16(am[r], bn[c], acc[r][c], 0, 0, 0);
        __syncthreads();
    }

    const float bsf = bias[h];
    float* outB = out + ((size_t)h << 20) + ((size_t)n0 << 10) + m0;
    const int mq = (lane >> 4) * 4;
#pragma unroll
    for (int r = 0; r < 4; ++r) {
#pragma unroll
        for (int c = 0; c < 4; ++c) {
            const int n = nb + c * 16 + fr;
            const int m = mbw + r * 16 + mq;
            float4 o;
            float v0 = acc[r][c][0] + bsf; o.x = (v0 >= 0.f) ? v0 : 0.2f * v0;
            float v1 = acc[r][c][1] + bsf; o.y = (v1 >= 0.f) ? v1 : 0.2f * v1;
            float v2 = acc[r][c][2] + bsf; o.z = (v2 >= 0.f) ? v2 : 0.2f * v2;
            float v3 = acc[r][c][3] + bsf; o.w = (v3 >= 0.f) ? v3 : 0.2f * v3;
            *(float4*)(outB + ((size_t)n << 10) + m) = o;
        }
    }
}

extern "C" void kernel_launch(void* const* d_in, const int* in_sizes, int n_in,
                              void* d_out, int out_size, void* d_ws, size_t ws_size,
                              hipStream_t stream) {
    (void)in_sizes; (void)n_in; (void)out_size;
    const float* z0   = (const float*)d_in[0];
    const float* z1   = (const float*)d_in[1];
    const float* Wm   = (const float*)d_in[2];
    const float* bias = (const float*)d_in[3];
    float* out = (float*)d_out;

    const size_t aall_bytes = (size_t)128 * 1024 * 256 * 2;           // 64 MiB
    const size_t need = aall_bytes + (size_t)1024 * 256 * 2;          // + 512 KiB
    if (ws_size >= need) {
        uint16_t* Aall = (uint16_t*)d_ws;
        uint16_t* Bbf  = (uint16_t*)((char*)d_ws + aall_bytes);
        prep_kernel<<<16512, 256, 0, stream>>>(z0, z1, Wm, Aall, Bbf);
        gemm_kernel<<<8192, 256, 0, stream>>>(Aall, Bbf, bias, out);
    } else {
        dim3 grid(8, 8, 128), block(256);
        gemm_fb<<<grid, block, 0, stream>>>(z0, z1, Wm, bias, out);
    }
}